// Round 5
// baseline (736.148 us; speedup 1.0000x reference)
//
#include <hip/hip_runtime.h>

#define B_  2
#define S_  2048
#define D_  512
#define H_  8
#define E_  512
#define HE_ 4096

typedef _Float16 half8_t  __attribute__((ext_vector_type(8)));
typedef _Float16 half4_t  __attribute__((ext_vector_type(4)));
typedef float    floatx4  __attribute__((ext_vector_type(4)));
typedef __attribute__((address_space(1))) const unsigned int* gas_ptr;
typedef __attribute__((address_space(3))) unsigned int*       las_ptr;

// ---------------- cast fp32 -> fp16 (vectorized) ----------------
__global__ __launch_bounds__(256) void cast_f16_kernel(const float* __restrict__ src,
                                                       _Float16* __restrict__ dst, int n4) {
    int i = blockIdx.x * 256 + threadIdx.x;
    if (i >= n4) return;
    float4 v = ((const float4*)src)[i];
    half4_t h = { (_Float16)v.x, (_Float16)v.y, (_Float16)v.z, (_Float16)v.w };
    ((half4_t*)dst)[i] = h;
}

// ------------- transpose + cast: src fp32 [R,C] -> dst fp16 [C,R], batched -------------
__global__ __launch_bounds__(256) void transpose_cast_kernel(const float* __restrict__ src,
                                                             _Float16* __restrict__ dst,
                                                             int R, int C) {
    __shared__ float t[32][33];
    long long zoff = (long long)blockIdx.z * R * C;
    src += zoff; dst += zoff;
    int c0 = blockIdx.x * 32, r0 = blockIdx.y * 32;
    int tx = threadIdx.x, ty = threadIdx.y;
#pragma unroll
    for (int i = 0; i < 32; i += 8)
        t[ty + i][tx] = src[(long long)(r0 + ty + i) * C + (c0 + tx)];
    __syncthreads();
#pragma unroll
    for (int i = 0; i < 32; i += 8)
        dst[(long long)(c0 + ty + i) * R + (r0 + tx)] = (_Float16)t[tx][ty + i];
}

// ------------- bt-GEMM (round-3 body): C[M,N] = A[M,K]*Bt[N,K]^T (+bias, +mask->-60000) --
// 128x128 tile, 4 waves 2x2, wave = 64x64 via 4x4 mfma_f32_16x16x32_f16.
// NOTE r4 lesson: do NOT serialize af loads, do NOT cap regs with launch_bounds(,4) —
// MfmaUtil dropped 20->14 despite 2x occupancy. Keep the 8-upfront-ds_read form.
__global__ __launch_bounds__(256) void gemm_bt_kernel(
    const _Float16* __restrict__ A, const _Float16* __restrict__ Bt,
    const float* __restrict__ bias,
    const int* __restrict__ mask, long long m_z, int m_rs, int mdiv,
    void* __restrict__ C, int out_f32,
    int K, int lda, int ldb,
    long long a_b, long long a_h, long long b_b, long long b_h,
    long long c_b, long long c_h, int c_rs, int c_cs,
    int divh, int bias_h)
{
    int z  = blockIdx.z;
    int bb = z / divh, hh = z % divh;
    A  += bb * a_b + hh * a_h;
    Bt += bb * b_b + hh * b_h;
    long long coff = bb * c_b + hh * c_h;

    int m0 = blockIdx.y * 128;
    int n0 = blockIdx.x * 128;

    __shared__ __align__(16) _Float16 As[128][32];   // 8 KB, NO padding (global_load_lds)
    __shared__ __align__(16) _Float16 Bs[128][32];   // 8 KB

    int tid  = threadIdx.x;
    int wave = tid >> 6, lane = tid & 63;
    int quad = lane >> 4, l16 = lane & 15;
    int wy = (wave >> 1) * 64, wx = (wave & 1) * 64;

    int srow = (wave << 4) + (lane >> 2);
    int scol = (lane & 3) * 8;
    _Float16* lA0 = &As[0][0] + (wave << 9);
    _Float16* lB0 = &Bs[0][0] + (wave << 9);

    floatx4 acc[4][4] = {};

    for (int k0 = 0; k0 < K; k0 += 32) {
        if (k0) __syncthreads();
        const _Float16* gA = A + (long long)(m0 + srow) * lda + k0 + scol;
        const _Float16* gB = Bt + (long long)(n0 + srow) * ldb + k0 + scol;
#pragma unroll
        for (int j = 0; j < 2; j++) {
            __builtin_amdgcn_global_load_lds((gas_ptr)(gA + (long long)(j << 6) * lda),
                                             (las_ptr)(lA0 + (j << 11)), 16, 0, 0);
            __builtin_amdgcn_global_load_lds((gas_ptr)(gB + (long long)(j << 6) * ldb),
                                             (las_ptr)(lB0 + (j << 11)), 16, 0, 0);
        }
        __syncthreads();

        half8_t af[4], bf[4];
#pragma unroll
        for (int i = 0; i < 4; i++) {
            af[i] = *(const half8_t*)&As[wy + i * 16 + l16][quad * 8];
            bf[i] = *(const half8_t*)&Bs[wx + i * 16 + l16][quad * 8];
        }
#pragma unroll
        for (int mi = 0; mi < 4; mi++)
#pragma unroll
            for (int ni = 0; ni < 4; ni++)
                acc[mi][ni] = __builtin_amdgcn_mfma_f32_16x16x32_f16(af[mi], bf[ni], acc[mi][ni], 0, 0, 0);
    }

    const int* mz = mask ? (mask + (z / mdiv) * m_z) : (const int*)0;
    float*    fC = (float*)C;
    _Float16* hC = (_Float16*)C;
#pragma unroll
    for (int mi = 0; mi < 4; mi++)
#pragma unroll
        for (int ni = 0; ni < 4; ni++)
#pragma unroll
            for (int r = 0; r < 4; r++) {
                int row = m0 + wy + mi * 16 + quad * 4 + r;
                int col = n0 + wx + ni * 16 + l16;
                float v = acc[mi][ni][r];
                if (bias) v += bias[hh * bias_h + col];
                if (mz && !mz[(long long)row * m_rs + col]) v = -60000.0f;
                long long addr = coff + (long long)row * c_rs + (long long)col * c_cs;
                if (out_f32) fC[addr] = v; else hC[addr] = (_Float16)v;
            }
}

// ------------- softmax over pre-masked fp16 score rows, in place, wave-per-row ----------
// grid (S/4, 1, Z); block 256 = 4 waves; wave w owns row blockIdx.x*4+w.
// Lane-contiguous half8 loads (16B/lane), shuffle-only reductions — no LDS, no barriers.
__global__ __launch_bounds__(256) void softmax_rows_kernel(_Float16* __restrict__ sc)
{
    long long z = blockIdx.z;
    int wave = threadIdx.x >> 6, lane = threadIdx.x & 63;
    int s = blockIdx.x * 4 + wave;
    _Float16* row = sc + z * ((long long)S_ * S_) + (long long)s * S_;

    half8_t h[4];
    float v[32];
    float mx = -3.0e38f;
#pragma unroll
    for (int j = 0; j < 4; j++) {
        h[j] = *(const half8_t*)(row + j * 512 + lane * 8);
#pragma unroll
        for (int e = 0; e < 8; e++) {
            v[j * 8 + e] = (float)h[j][e];
            mx = fmaxf(mx, v[j * 8 + e]);
        }
    }
#pragma unroll
    for (int o = 32; o > 0; o >>= 1) mx = fmaxf(mx, __shfl_xor(mx, o));

    float sum = 0.0f;
#pragma unroll
    for (int i = 0; i < 32; i++) { v[i] = __expf(v[i] - mx); sum += v[i]; }
#pragma unroll
    for (int o = 32; o > 0; o >>= 1) sum += __shfl_xor(sum, o);

    float inv = 1.0f / sum;
#pragma unroll
    for (int j = 0; j < 4; j++) {
#pragma unroll
        for (int e = 0; e < 8; e++) h[j][e] = (_Float16)(v[j * 8 + e] * inv);
        *(half8_t*)(row + j * 512 + lane * 8) = h[j];
    }
}

// ------------- split-K bt-GEMM, 128(M)x64(N) tile, fp32 atomic accumulate ---------------
__global__ __launch_bounds__(256) void gemm_bt_n64_splitk_kernel(
    const _Float16* __restrict__ A, const _Float16* __restrict__ Bt,
    const float* __restrict__ bias, float* __restrict__ C,
    int K, int lda, int ldb, int ldc, int ksplit)
{
    int m0 = blockIdx.y * 128;
    int n0 = blockIdx.x * 64;
    int kchunk = K / ksplit;
    int kbeg = blockIdx.z * kchunk;
    int kend = kbeg + kchunk;

    __shared__ __align__(16) _Float16 As[128][32];
    __shared__ __align__(16) _Float16 Bs[64][32];

    int tid  = threadIdx.x;
    int wave = tid >> 6, lane = tid & 63;
    int quad = lane >> 4, l16 = lane & 15;
    int wy = (wave >> 1) * 64, wx = (wave & 1) * 32;

    int srow = (wave << 4) + (lane >> 2);
    int scol = (lane & 3) * 8;
    _Float16* lA0 = &As[0][0] + (wave << 9);
    _Float16* lB0 = &Bs[0][0] + (wave << 9);

    floatx4 acc[4][2] = {};

    for (int k0 = kbeg; k0 < kend; k0 += 32) {
        if (k0 != kbeg) __syncthreads();
        const _Float16* gA = A + (long long)(m0 + srow) * lda + k0 + scol;
        const _Float16* gB = Bt + (long long)(n0 + srow) * ldb + k0 + scol;
#pragma unroll
        for (int j = 0; j < 2; j++)
            __builtin_amdgcn_global_load_lds((gas_ptr)(gA + (long long)(j << 6) * lda),
                                             (las_ptr)(lA0 + (j << 11)), 16, 0, 0);
        __builtin_amdgcn_global_load_lds((gas_ptr)gB, (las_ptr)lB0, 16, 0, 0);
        __syncthreads();

        half8_t af[4], bf[2];
#pragma unroll
        for (int i = 0; i < 4; i++)
            af[i] = *(const half8_t*)&As[wy + i * 16 + l16][quad * 8];
#pragma unroll
        for (int i = 0; i < 2; i++)
            bf[i] = *(const half8_t*)&Bs[wx + i * 16 + l16][quad * 8];
#pragma unroll
        for (int mi = 0; mi < 4; mi++)
#pragma unroll
            for (int ni = 0; ni < 2; ni++)
                acc[mi][ni] = __builtin_amdgcn_mfma_f32_16x16x32_f16(af[mi], bf[ni], acc[mi][ni], 0, 0, 0);
    }

    int addb = (blockIdx.z == 0) && bias;
#pragma unroll
    for (int mi = 0; mi < 4; mi++)
#pragma unroll
        for (int ni = 0; ni < 2; ni++)
#pragma unroll
            for (int r = 0; r < 4; r++) {
                int row = m0 + wy + mi * 16 + quad * 4 + r;
                int col = n0 + wx + ni * 16 + l16;
                float v = acc[mi][ni][r];
                if (addb) v += bias[col];
                atomicAdd(&C[(long long)row * ldc + col], v);
            }
}

extern "C" void kernel_launch(void* const* d_in, const int* in_sizes, int n_in,
                              void* d_out, int out_size, void* d_ws, size_t ws_size,
                              hipStream_t stream)
{
    const float* qin = (const float*)d_in[0];
    const float* kin = (const float*)d_in[1];
    const float* vin = (const float*)d_in[2];
    const int*   mask = (const int*)d_in[3];
    const float* Wq = (const float*)d_in[4];
    const float* bq = (const float*)d_in[5];
    const float* Wk = (const float*)d_in[6];
    const float* bk = (const float*)d_in[7];
    const float* Wv = (const float*)d_in[8];
    const float* bv = (const float*)d_in[9];
    const float* Wo = (const float*)d_in[10];
    const float* bo = (const float*)d_in[11];
    float* out = (float*)d_out;

    char* ws = (char*)d_ws;
    size_t off = 0;
    _Float16* WoT = (_Float16*)(ws + off); off += (size_t)E_ * HE_ * 2;           // 4 MiB
    _Float16* Qb  = (_Float16*)(ws + off); off += (size_t)B_ * H_ * S_ * E_ * 2;  // 32 MiB
    _Float16* Kb  = (_Float16*)(ws + off); off += (size_t)B_ * H_ * S_ * E_ * 2;  // 32 MiB
    _Float16* VT  = (_Float16*)(ws + off); off += (size_t)B_ * H_ * E_ * S_ * 2;  // 32 MiB
    size_t region = off;
    _Float16* Xq  = (_Float16*)(ws + region);
    _Float16* Xk  = Xq  + (size_t)B_ * S_ * D_;
    _Float16* Xv  = Xk  + (size_t)B_ * S_ * D_;
    _Float16* WqT = Xv  + (size_t)B_ * S_ * D_;
    _Float16* WkT = WqT + (size_t)H_ * E_ * D_;
    _Float16* WvT = WkT + (size_t)H_ * E_ * D_;
    _Float16* SC  = (_Float16*)(ws + region);   // fp16 masked scores -> normalized P
    _Float16* cat = Qb;                          // aliases Q (dead after scores GEMM)

    long long SE = (long long)S_ * E_;
    long long SS = (long long)S_ * S_;
    long long ES = (long long)E_ * S_;
    long long SD = (long long)S_ * D_;
    long long ED = (long long)E_ * D_;

    auto gemm = [&](const _Float16* A, const _Float16* Bt, const float* bias,
                    const int* msk, long long mz, int mrs, int mdiv,
                    void* C, int f32, int M, int N, int K, int lda, int ldb,
                    long long ab, long long ah, long long bb2, long long bh,
                    long long cb, long long ch, int rs, int cs,
                    int divh, int biash, int nz) {
        gemm_bt_kernel<<<dim3(N / 128, M / 128, nz), 256, 0, stream>>>(
            A, Bt, bias, msk, mz, mrs, mdiv, C, f32, K, lda, ldb,
            ab, ah, bb2, bh, cb, ch, rs, cs, divh, biash);
    };

    // zero d_out (split-K atomic accumulation target)
    hipMemsetAsync(d_out, 0, (size_t)out_size * sizeof(float), stream);

    // 1) cast inputs to fp16
    int n4 = B_ * S_ * D_ / 4;
    cast_f16_kernel<<<dim3(n4 / 256), 256, 0, stream>>>(qin, Xq, n4);
    cast_f16_kernel<<<dim3(n4 / 256), 256, 0, stream>>>(kin, Xk, n4);
    cast_f16_kernel<<<dim3(n4 / 256), 256, 0, stream>>>(vin, Xv, n4);

    // 2) transpose+cast weights to Bt form
    dim3 tb(32, 8);
    transpose_cast_kernel<<<dim3(E_ / 32, D_ / 32, H_), tb, 0, stream>>>(Wq, WqT, D_, E_);
    transpose_cast_kernel<<<dim3(E_ / 32, D_ / 32, H_), tb, 0, stream>>>(Wk, WkT, D_, E_);
    transpose_cast_kernel<<<dim3(E_ / 32, D_ / 32, H_), tb, 0, stream>>>(Wv, WvT, D_, E_);
    transpose_cast_kernel<<<dim3(E_ / 32, HE_ / 32, 1), tb, 0, stream>>>(Wo, WoT, HE_, E_);

    // 3) projections: Q,K -> [B,H,S,E]; V -> VT [B,H,E,S] via strided epilogue store
    gemm(Xq, WqT, bq, nullptr, 0, 0, 1, Qb, 0, S_, E_, D_, D_, D_,
         SD, 0, 0, ED, (long long)H_ * SE, SE, E_, 1, H_, E_, B_ * H_);
    gemm(Xk, WkT, bk, nullptr, 0, 0, 1, Kb, 0, S_, E_, D_, D_, D_,
         SD, 0, 0, ED, (long long)H_ * SE, SE, E_, 1, H_, E_, B_ * H_);
    gemm(Xv, WvT, bv, nullptr, 0, 0, 1, VT, 0, S_, E_, D_, D_, D_,
         SD, 0, 0, ED, (long long)H_ * ES, ES, 1, S_, H_, E_, B_ * H_);

    // 4a) masked raw scores (mask fused into epilogue; masked -> -60000)
    gemm(Qb, Kb, nullptr, mask, SS, S_, H_, SC, 0, S_, S_, E_, E_, E_,
         0, SE, 0, SE, 0, SS, S_, 1, B_ * H_ * 2 /*divh>z: bb=0,hh=z*/, 0, B_ * H_);

    // 4b) softmax in place (scores already masked -> no mask traffic here)
    softmax_rows_kernel<<<dim3(S_ / 4, 1, B_ * H_), 256, 0, stream>>>(SC);

    // 4c) P @ V -> cat[b,s,h*E+e]
    gemm(SC, VT, nullptr, nullptr, 0, 0, 1, cat, 0, S_, E_, S_, S_, S_,
         (long long)H_ * SS, SS, (long long)H_ * ES, ES,
         (long long)S_ * HE_, E_, HE_, 1, H_, 0, B_ * H_);

    // 5) output projection: split-K (4) 128x64-tile GEMM, atomic fp32 accumulate
    gemm_bt_n64_splitk_kernel<<<dim3(E_ / 64, (B_ * S_) / 128, 4), 256, 0, stream>>>(
        cat, WoT, bo, out, HE_, HE_, HE_, E_, 4);
}

// Round 6
// 611.190 us; speedup vs baseline: 1.2045x; 1.2045x over previous
//
#include <hip/hip_runtime.h>

#define B_  2
#define S_  2048
#define D_  512
#define H_  8
#define E_  512
#define HE_ 4096

typedef _Float16 half8_t  __attribute__((ext_vector_type(8)));
typedef _Float16 half4_t  __attribute__((ext_vector_type(4)));
typedef float    floatx4  __attribute__((ext_vector_type(4)));
typedef __attribute__((address_space(1))) const unsigned int* gas_ptr;
typedef __attribute__((address_space(3))) unsigned int*       las_ptr;

// ---------------- fused cast fp32 -> fp16 for q,k,v (vectorized) ----------------
__global__ __launch_bounds__(256) void cast3_f16_kernel(
    const float* __restrict__ s0, const float* __restrict__ s1, const float* __restrict__ s2,
    _Float16* __restrict__ d0, _Float16* __restrict__ d1, _Float16* __restrict__ d2, int n4) {
    int i = blockIdx.x * 256 + threadIdx.x;
    if (i >= n4) return;
    const float* s = (blockIdx.y == 0) ? s0 : (blockIdx.y == 1) ? s1 : s2;
    _Float16*    d = (blockIdx.y == 0) ? d0 : (blockIdx.y == 1) ? d1 : d2;
    float4 v = ((const float4*)s)[i];
    half4_t h = { (_Float16)v.x, (_Float16)v.y, (_Float16)v.z, (_Float16)v.w };
    ((half4_t*)d)[i] = h;
}

// ------------- transpose + cast: src fp32 [R,C] -> dst fp16 [C,R], batched -------------
__global__ __launch_bounds__(256) void transpose_cast_kernel(const float* __restrict__ src,
                                                             _Float16* __restrict__ dst,
                                                             int R, int C) {
    __shared__ float t[32][33];
    long long zoff = (long long)blockIdx.z * R * C;
    src += zoff; dst += zoff;
    int c0 = blockIdx.x * 32, r0 = blockIdx.y * 32;
    int tx = threadIdx.x, ty = threadIdx.y;
#pragma unroll
    for (int i = 0; i < 32; i += 8)
        t[ty + i][tx] = src[(long long)(r0 + ty + i) * C + (c0 + tx)];
    __syncthreads();
#pragma unroll
    for (int i = 0; i < 32; i += 8)
        dst[(long long)(c0 + ty + i) * R + (r0 + tx)] = (_Float16)t[tx][ty + i];
}

// ------------- bt-GEMM: C[M,N] = A[M,K]*Bt[N,K]^T (+bias[n]) -------------
// 128x128 tile, 4 waves 2x2, wave = 64x64 via 4x4 mfma_f32_16x16x32_f16.
// BK=64 as TWO k-panels As[2][128][32]: barrier count halved vs BK=32 while
// keeping 64B LDS row stride (same 8-way-bank pattern as BK=32; a flat
// [128][64] layout would be 16-way conflicted). NO mask epilogue (r5 lesson:
// scattered epilogue loads thrash caches + stall block turnover).
__global__ __launch_bounds__(256) void gemm_bt_kernel(
    const _Float16* __restrict__ A, const _Float16* __restrict__ Bt,
    const float* __restrict__ bias, void* __restrict__ C, int out_f32,
    int K, int lda, int ldb,
    long long a_b, long long a_h, long long b_b, long long b_h,
    long long c_b, long long c_h, int c_rs, int c_cs,
    int divh, int bias_h)
{
    int z  = blockIdx.z;
    int bb = z / divh, hh = z % divh;
    A  += bb * a_b + hh * a_h;
    Bt += bb * b_b + hh * b_h;
    long long coff = bb * c_b + hh * c_h;

    int m0 = blockIdx.y * 128;
    int n0 = blockIdx.x * 128;

    __shared__ __align__(16) _Float16 As[2][128][32];   // 16 KB (k-panels)
    __shared__ __align__(16) _Float16 Bs[2][128][32];   // 16 KB

    int tid  = threadIdx.x;
    int wave = tid >> 6, lane = tid & 63;
    int quad = lane >> 4, l16 = lane & 15;
    int wy = (wave >> 1) * 64, wx = (wave & 1) * 64;

    // staging: wave w -> panel (w&1), rows [(w>>1)*64 .. +64), 4 instrs x 16 rows each
    int pw = wave & 1;
    int rw = (wave >> 1) * 64;
    int sr = lane >> 2;            // 0..15 (+ j*16)
    int sc = (lane & 3) * 8;       // 0..24
    _Float16* lA0 = &As[pw][rw][0];   // + j*512 elems; HW adds lane*16B
    _Float16* lB0 = &Bs[pw][rw][0];

    floatx4 acc[4][4] = {};

    for (int k0 = 0; k0 < K; k0 += 64) {
        if (k0) __syncthreads();
        const _Float16* gA = A + (long long)(m0 + rw + sr) * lda + k0 + pw * 32 + sc;
        const _Float16* gB = Bt + (long long)(n0 + rw + sr) * ldb + k0 + pw * 32 + sc;
#pragma unroll
        for (int j = 0; j < 4; j++) {
            __builtin_amdgcn_global_load_lds((gas_ptr)(gA + (long long)(j * 16) * lda),
                                             (las_ptr)(lA0 + j * 512), 16, 0, 0);
            __builtin_amdgcn_global_load_lds((gas_ptr)(gB + (long long)(j * 16) * ldb),
                                             (las_ptr)(lB0 + j * 512), 16, 0, 0);
        }
        __syncthreads();

#pragma unroll
        for (int kc = 0; kc < 2; kc++) {
            half8_t af[4], bf[4];
#pragma unroll
            for (int i = 0; i < 4; i++) {
                af[i] = *(const half8_t*)&As[kc][wy + i * 16 + l16][quad * 8];
                bf[i] = *(const half8_t*)&Bs[kc][wx + i * 16 + l16][quad * 8];
            }
#pragma unroll
            for (int mi = 0; mi < 4; mi++)
#pragma unroll
                for (int ni = 0; ni < 4; ni++)
                    acc[mi][ni] = __builtin_amdgcn_mfma_f32_16x16x32_f16(af[mi], bf[ni], acc[mi][ni], 0, 0, 0);
        }
    }

    float*    fC = (float*)C;
    _Float16* hC = (_Float16*)C;
#pragma unroll
    for (int mi = 0; mi < 4; mi++)
#pragma unroll
        for (int ni = 0; ni < 4; ni++)
#pragma unroll
            for (int r = 0; r < 4; r++) {
                int row = m0 + wy + mi * 16 + quad * 4 + r;
                int col = n0 + wx + ni * 16 + l16;
                float v = acc[mi][ni][r];
                if (bias) v += bias[hh * bias_h + col];
                long long addr = coff + (long long)row * c_rs + (long long)col * c_cs;
                if (out_f32) fC[addr] = v; else hC[addr] = (_Float16)v;
            }
}

// ------------- masked softmax, 8 heads per block (mask row reused via L1) -------------
// grid (S, 1, B); block 512 = 8 waves; wave h owns the full score row of head h
// at (b, s). Lane-contiguous half8/int4 loads; shuffle-only reduction (row fits
// one wave: 64 lanes x 32 elems = 2048). Masked -> -1e9 in fp32, then softmax.
__global__ __launch_bounds__(512) void softmax_mask8_kernel(_Float16* __restrict__ sc,
                                                            const int* __restrict__ mask)
{
    int b = blockIdx.z, s = blockIdx.x;
    int wave = threadIdx.x >> 6, lane = threadIdx.x & 63;
    _Float16* row = sc + ((long long)(b * H_ + wave) * S_ + s) * S_;
    const int* mrow = mask + ((long long)b * S_ + s) * S_;

    half8_t h[4];
    float v[32];
    float mx = -3.0e38f;
#pragma unroll
    for (int j = 0; j < 4; j++) {
        int c = j * 512 + lane * 8;
        h[j] = *(const half8_t*)(row + c);
        int4 mA = *(const int4*)(mrow + c);
        int4 mB = *(const int4*)(mrow + c + 4);
        int mm[8] = { mA.x, mA.y, mA.z, mA.w, mB.x, mB.y, mB.z, mB.w };
#pragma unroll
        for (int e = 0; e < 8; e++) {
            float val = mm[e] ? (float)h[j][e] : -1.0e9f;
            v[j * 8 + e] = val;
            mx = fmaxf(mx, val);
        }
    }
#pragma unroll
    for (int o = 32; o > 0; o >>= 1) mx = fmaxf(mx, __shfl_xor(mx, o));

    float sum = 0.0f;
#pragma unroll
    for (int i = 0; i < 32; i++) { v[i] = __expf(v[i] - mx); sum += v[i]; }
#pragma unroll
    for (int o = 32; o > 0; o >>= 1) sum += __shfl_xor(sum, o);

    float inv = 1.0f / sum;
#pragma unroll
    for (int j = 0; j < 4; j++) {
#pragma unroll
        for (int e = 0; e < 8; e++) h[j][e] = (_Float16)(v[j * 8 + e] * inv);
        *(half8_t*)(row + j * 512 + lane * 8) = h[j];
    }
}

// ------------- split-K bt-GEMM, 128(M)x64(N) tile, fp32 atomic accumulate ---------------
__global__ __launch_bounds__(256) void gemm_bt_n64_splitk_kernel(
    const _Float16* __restrict__ A, const _Float16* __restrict__ Bt,
    const float* __restrict__ bias, float* __restrict__ C,
    int K, int lda, int ldb, int ldc, int ksplit)
{
    int m0 = blockIdx.y * 128;
    int n0 = blockIdx.x * 64;
    int kchunk = K / ksplit;
    int kbeg = blockIdx.z * kchunk;
    int kend = kbeg + kchunk;

    __shared__ __align__(16) _Float16 As[128][32];
    __shared__ __align__(16) _Float16 Bs[64][32];

    int tid  = threadIdx.x;
    int wave = tid >> 6, lane = tid & 63;
    int quad = lane >> 4, l16 = lane & 15;
    int wy = (wave >> 1) * 64, wx = (wave & 1) * 32;

    int srow = (wave << 4) + (lane >> 2);
    int scol = (lane & 3) * 8;
    _Float16* lA0 = &As[0][0] + (wave << 9);
    _Float16* lB0 = &Bs[0][0] + (wave << 9);

    floatx4 acc[4][2] = {};

    for (int k0 = kbeg; k0 < kend; k0 += 32) {
        if (k0 != kbeg) __syncthreads();
        const _Float16* gA = A + (long long)(m0 + srow) * lda + k0 + scol;
        const _Float16* gB = Bt + (long long)(n0 + srow) * ldb + k0 + scol;
#pragma unroll
        for (int j = 0; j < 2; j++)
            __builtin_amdgcn_global_load_lds((gas_ptr)(gA + (long long)(j << 6) * lda),
                                             (las_ptr)(lA0 + (j << 11)), 16, 0, 0);
        __builtin_amdgcn_global_load_lds((gas_ptr)gB, (las_ptr)lB0, 16, 0, 0);
        __syncthreads();

        half8_t af[4], bf[2];
#pragma unroll
        for (int i = 0; i < 4; i++)
            af[i] = *(const half8_t*)&As[wy + i * 16 + l16][quad * 8];
#pragma unroll
        for (int i = 0; i < 2; i++)
            bf[i] = *(const half8_t*)&Bs[wx + i * 16 + l16][quad * 8];
#pragma unroll
        for (int mi = 0; mi < 4; mi++)
#pragma unroll
            for (int ni = 0; ni < 2; ni++)
                acc[mi][ni] = __builtin_amdgcn_mfma_f32_16x16x32_f16(af[mi], bf[ni], acc[mi][ni], 0, 0, 0);
    }

    int addb = (blockIdx.z == 0) && bias;
#pragma unroll
    for (int mi = 0; mi < 4; mi++)
#pragma unroll
        for (int ni = 0; ni < 2; ni++)
#pragma unroll
            for (int r = 0; r < 4; r++) {
                int row = m0 + wy + mi * 16 + quad * 4 + r;
                int col = n0 + wx + ni * 16 + l16;
                float v = acc[mi][ni][r];
                if (addb) v += bias[col];
                atomicAdd(&C[(long long)row * ldc + col], v);
            }
}

extern "C" void kernel_launch(void* const* d_in, const int* in_sizes, int n_in,
                              void* d_out, int out_size, void* d_ws, size_t ws_size,
                              hipStream_t stream)
{
    const float* qin = (const float*)d_in[0];
    const float* kin = (const float*)d_in[1];
    const float* vin = (const float*)d_in[2];
    const int*   mask = (const int*)d_in[3];
    const float* Wq = (const float*)d_in[4];
    const float* bq = (const float*)d_in[5];
    const float* Wk = (const float*)d_in[6];
    const float* bk = (const float*)d_in[7];
    const float* Wv = (const float*)d_in[8];
    const float* bv = (const float*)d_in[9];
    const float* Wo = (const float*)d_in[10];
    const float* bo = (const float*)d_in[11];
    float* out = (float*)d_out;

    char* ws = (char*)d_ws;
    size_t off = 0;
    _Float16* WoT = (_Float16*)(ws + off); off += (size_t)E_ * HE_ * 2;           // 4 MiB
    _Float16* Qb  = (_Float16*)(ws + off); off += (size_t)B_ * H_ * S_ * E_ * 2;  // 32 MiB
    _Float16* Kb  = (_Float16*)(ws + off); off += (size_t)B_ * H_ * S_ * E_ * 2;  // 32 MiB
    _Float16* VT  = (_Float16*)(ws + off); off += (size_t)B_ * H_ * E_ * S_ * 2;  // 32 MiB
    size_t region = off;
    _Float16* Xq  = (_Float16*)(ws + region);
    _Float16* Xk  = Xq  + (size_t)B_ * S_ * D_;
    _Float16* Xv  = Xk  + (size_t)B_ * S_ * D_;
    _Float16* WqT = Xv  + (size_t)B_ * S_ * D_;
    _Float16* WkT = WqT + (size_t)H_ * E_ * D_;
    _Float16* WvT = WkT + (size_t)H_ * E_ * D_;
    _Float16* SC  = (_Float16*)(ws + region);   // fp16 scores -> normalized P (in place)
    _Float16* cat = Qb;                          // aliases Q (dead after scores GEMM)

    long long SE = (long long)S_ * E_;
    long long SS = (long long)S_ * S_;
    long long ES = (long long)E_ * S_;
    long long SD = (long long)S_ * D_;
    long long ED = (long long)E_ * D_;

    auto gemm = [&](const _Float16* A, const _Float16* Bt, const float* bias,
                    void* C, int f32, int M, int N, int K, int lda, int ldb,
                    long long ab, long long ah, long long bb2, long long bh,
                    long long cb, long long ch, int rs, int cs,
                    int divh, int biash, int nz) {
        gemm_bt_kernel<<<dim3(N / 128, M / 128, nz), 256, 0, stream>>>(
            A, Bt, bias, C, f32, K, lda, ldb, ab, ah, bb2, bh, cb, ch, rs, cs, divh, biash);
    };

    // zero d_out (split-K atomic accumulation target)
    hipMemsetAsync(d_out, 0, (size_t)out_size * sizeof(float), stream);

    // 1) cast q,k,v to fp16 (one fused launch)
    int n4 = B_ * S_ * D_ / 4;
    cast3_f16_kernel<<<dim3(n4 / 256, 3), 256, 0, stream>>>(qin, kin, vin, Xq, Xk, Xv, n4);

    // 2) transpose+cast weights to Bt form
    dim3 tb(32, 8);
    transpose_cast_kernel<<<dim3(E_ / 32, D_ / 32, H_), tb, 0, stream>>>(Wq, WqT, D_, E_);
    transpose_cast_kernel<<<dim3(E_ / 32, D_ / 32, H_), tb, 0, stream>>>(Wk, WkT, D_, E_);
    transpose_cast_kernel<<<dim3(E_ / 32, D_ / 32, H_), tb, 0, stream>>>(Wv, WvT, D_, E_);
    transpose_cast_kernel<<<dim3(E_ / 32, HE_ / 32, 1), tb, 0, stream>>>(Wo, WoT, HE_, E_);

    // 3) projections: Q,K -> [B,H,S,E]; V -> VT [B,H,E,S] via strided epilogue store
    gemm(Xq, WqT, bq, Qb, 0, S_, E_, D_, D_, D_,
         SD, 0, 0, ED, (long long)H_ * SE, SE, E_, 1, H_, E_, B_ * H_);
    gemm(Xk, WkT, bk, Kb, 0, S_, E_, D_, D_, D_,
         SD, 0, 0, ED, (long long)H_ * SE, SE, E_, 1, H_, E_, B_ * H_);
    gemm(Xv, WvT, bv, VT, 0, S_, E_, D_, D_, D_,
         SD, 0, 0, ED, (long long)H_ * ES, ES, 1, S_, H_, E_, B_ * H_);

    // 4a) raw scores (UNmasked — mask handled in softmax; r5 lesson)
    gemm(Qb, Kb, nullptr, SC, 0, S_, S_, E_, E_, E_,
         0, SE, 0, SE, 0, SS, S_, 1, B_ * H_ * 2 /*divh>z: bb=0,hh=z*/, 0, B_ * H_);

    // 4b) masked softmax in place, 8 heads per block
    softmax_mask8_kernel<<<dim3(S_, 1, B_), 512, 0, stream>>>(SC, mask);

    // 4c) P @ V -> cat[b,s,h*E+e]
    gemm(SC, VT, nullptr, cat, 0, S_, E_, S_, S_, S_,
         (long long)H_ * SS, SS, (long long)H_ * ES, ES,
         (long long)S_ * HE_, E_, HE_, 1, H_, 0, B_ * H_);

    // 5) output projection: split-K (4) 128x64-tile GEMM, atomic fp32 accumulate
    gemm_bt_n64_splitk_kernel<<<dim3(E_ / 64, (B_ * S_) / 128, 4), 256, 0, stream>>>(
        cat, WoT, bo, out, HE_, HE_, HE_, E_, 4);
}